// Round 1
// baseline (862.342 us; speedup 1.0000x reference)
//
#include <hip/hip_runtime.h>

#define NNODES 65536
#define CC 128
#define NEL 10
#define BN 64
#define NT 512

#define INV_SQ2f 0.70710678118654752440f
#define INV_SQ6f 0.40824829046386301637f
#define INV_2Cf  0.0625f               /* 1/sqrt(256) */
#define INV_Cf   0.08838834764831845f  /* 1/sqrt(128) */
#define S16f 0.25f
#define S64f 0.125f

__device__ __forceinline__ float silu_f(float x) {
    return x * (1.0f / (1.0f + __expf(-x)));
}

__device__ __forceinline__ float dot4(float4 a, float4 b) {
    return a.x*b.x + a.y*b.y + a.z*b.z + a.w*b.w;
}

// load 4 consecutive-k weights of column o (row stride = stride), pre-scaled
__device__ __forceinline__ float4 ldw4(const float* __restrict__ W, int k, int stride, int o, float sc) {
    return make_float4(W[(k+0)*stride + o]*sc, W[(k+1)*stride + o]*sc,
                       W[(k+2)*stride + o]*sc, W[(k+3)*stride + o]*sc);
}

// dense layer, 64-wide output: out[n][j] = act(scale * sum_k in[n][k]*W[k][j])
// 512 threads: j = tid&63, 8 node-groups of 8
template<int KIN, bool ACT>
__device__ __forceinline__ void layer64(const float* __restrict__ inL,
                                        const float* __restrict__ W,
                                        float* __restrict__ outL,
                                        float scale, int tid)
{
    const int j = tid & 63;
    const int g = tid >> 6;
    float acc[8];
    #pragma unroll
    for (int nn = 0; nn < 8; ++nn) acc[nn] = 0.0f;
    #pragma unroll 4
    for (int k = 0; k < KIN; ++k) {
        const float w = W[k*64 + j];
        #pragma unroll
        for (int nn = 0; nn < 8; ++nn)
            acc[nn] += inL[(g*8 + nn)*KIN + k] * w;   // wave-uniform addr: LDS broadcast
    }
    #pragma unroll
    for (int nn = 0; nn < 8; ++nn) {
        const float x = acc[nn] * scale;
        outL[(g*8 + nn)*64 + j] = ACT ? silu_f(x) : x;
    }
}

// GEMM from LDS h[64][64] to 128-wide output; thread owns columns {o2, o2+64}, 8 nodes
__device__ __forceinline__ void gemm_h128(const float* __restrict__ hL,
                                          const float* __restrict__ W, int wrow,
                                          float scale, float* accA, float* accB,
                                          int o2, int g)
{
    #pragma unroll
    for (int nn = 0; nn < 8; ++nn) { accA[nn] = 0.0f; accB[nn] = 0.0f; }
    for (int k = 0; k < 64; k += 4) {
        const float4 wa = ldw4(W, k, wrow, o2, 1.0f);
        const float4 wb = ldw4(W, k, wrow, o2 + 64, 1.0f);
        #pragma unroll
        for (int nn = 0; nn < 8; ++nn) {
            const float4 h = *(const float4*)&hL[(g*8 + nn)*64 + k];
            accA[nn] += dot4(h, wa);
            accB[nn] += dot4(h, wb);
        }
    }
    #pragma unroll
    for (int nn = 0; nn < 8; ++nn) { accA[nn] *= scale; accB[nn] *= scale; }
}

extern "C" __global__ void __launch_bounds__(NT, 1)
epb_fused(const float* __restrict__ Sin, const float* __restrict__ Vin,
          const float* __restrict__ SCp, const float* __restrict__ ATT,
          const float* __restrict__ INVF, const float* __restrict__ MNA,
          const float* __restrict__ MLEN, const float* __restrict__ WSp,
          const float* __restrict__ WVp, const float* __restrict__ WC1,
          const float* __restrict__ WC2, const float* __restrict__ WC3,
          const float* __restrict__ WC4, const float* __restrict__ WB1,
          const float* __restrict__ WB2, const float* __restrict__ WB3,
          const float* __restrict__ WB4, const float* __restrict__ ESC,
          const float* __restrict__ WL0, const float* __restrict__ WL1,
          const float* __restrict__ WO0, const float* __restrict__ WO1,
          float* __restrict__ OUT)
{
    extern __shared__ float lds[];
    float* Ra   = lds;              // [64][128]: h ping/pong -> m1 -> b
    float* Rb   = Ra + BN*CC;       // [64][128]: ob -> m0 -> t
    float* Rc   = Rb + BN*CC;       // [64][128]: out_s -> a2 -> v_i staging
    float* Rd   = Rc + BN*CC;       // [64][128]: gate
    float* Eh   = Rd + BN*CC;       // [64][64] : h3 of Wc-chain
    float* invl = Eh + BN*64;       // [64][16]
    float* y0v  = invl + BN*16;     // [64]
    float* y1v  = y0v + BN;         // [64][3]
    float* etv  = y1v + BN*3;       // [64]
    float* hping = Ra;              // [64][64]
    float* hpong = Ra + BN*64;      // [64][64]
    __shared__ int eidx[BN];

    const int tid = threadIdx.x;
    const int n0  = blockIdx.x * BN;

    // ---- P0: per-node smalls ----
    for (int idx = tid; idx < BN*16; idx += NT)
        invl[idx] = INVF[n0*16 + idx];
    if (tid < BN) {
        const int gn = n0 + tid;
        y0v[tid] = MNA[gn*4 + 0];
        y1v[tid*3 + 0] = MNA[gn*4 + 1];
        y1v[tid*3 + 1] = MNA[gn*4 + 2];
        y1v[tid*3 + 2] = MNA[gn*4 + 3];
        etv[tid] = 1.0f - __expf(-ESC[0] * MLEN[gn]);
        int e = 0;
        #pragma unroll
        for (int k = 0; k < NEL; ++k)
            if (ATT[gn*NEL + k] > 0.5f) e = k;   // exact one-hot gather
        eidx[tid] = e;
    }
    __syncthreads();

    // ---- P1: both MLP chains ----
    layer64<16, true>(invl,  WC1, hping, S16f, tid); __syncthreads();
    layer64<64, true>(hping, WC2, hpong, S64f, tid); __syncthreads();
    layer64<64, true>(hpong, WC3, Eh,    S64f, tid); __syncthreads();
    layer64<16, true>(invl,  WB1, hping, S16f, tid); __syncthreads();
    layer64<64, true>(hping, WB2, hpong, S64f, tid); __syncthreads();
    layer64<64, true>(hpong, WB3, hping, S64f, tid); __syncthreads();
    {   // L4b: ob -> Rb
        const int o2 = tid & 63, g = tid >> 6;
        float oa[8], ob[8];
        gemm_h128(hping, WB4, CC, S64f, oa, ob, o2, g);
        #pragma unroll
        for (int nn = 0; nn < 8; ++nn) {
            const int n = g*8 + nn;
            Rb[n*CC + o2]      = oa[nn];
            Rb[n*CC + o2 + 64] = ob[nn];
        }
    }
    __syncthreads();

    // ---- P2: out_s -> Rc, gate -> Rd ----
    for (int idx = tid; idx < BN*CC; idx += NT) {
        const int n = idx >> 7, c = idx & (CC-1);
        const int gn = n0 + n;
        const float s = Sin[(size_t)gn*CC + c];
        const float* vp = Vin + (size_t)(gn*CC + c)*3;
        const float v0 = vp[0], v1 = vp[1], v2 = vp[2];
        const float vv = v0*v0 + v1*v1 + v2*v2;
        const int e = eidx[n];
        const float* wsp = WSp + (e*5)*CC + c;
        const float* wvp = WVp + (e*4)*CC + c;
        const float s2 = s*s;
        Rc[idx] = wsp[0]*s + wsp[CC]*s2 + wsp[2*CC]*vv + wsp[3*CC]*(s2*s) + wsp[4*CC]*(s*vv);
        Rd[idx] = wvp[0] + wvp[CC]*s + wvp[2*CC]*s2 + wvp[3*CC]*vv;
    }
    __syncthreads();

    // ---- P3: w1 chunk -> m1 (Ra); m1 = INV_SQ6*w1*gate*(v . y1) ----
    {
        const int o2 = tid & 63, g = tid >> 6;
        float wA[8], wB[8];
        gemm_h128(Eh, WC4 + CC, 512, S64f, wA, wB, o2, g);
        #pragma unroll
        for (int nn = 0; nn < 8; ++nn) {
            const int n = g*8 + nn, gn = n0 + n;
            const float yy0 = y1v[n*3], yy1 = y1v[n*3+1], yy2 = y1v[n*3+2];
            {
                const float* vp = Vin + (size_t)(gn*CC + o2)*3;
                const float vy = vp[0]*yy0 + vp[1]*yy1 + vp[2]*yy2;
                Ra[n*CC + o2] = INV_SQ6f * wA[nn] * Rd[n*CC + o2] * vy;
            }
            {
                const float* vp = Vin + (size_t)(gn*CC + o2 + 64)*3;
                const float vy = vp[0]*yy0 + vp[1]*yy1 + vp[2]*yy2;
                Ra[n*CC + o2 + 64] = INV_SQ6f * wB[nn] * Rd[n*CC + o2 + 64] * vy;
            }
        }
    }
    __syncthreads();

    // ---- P4: w0 chunk -> m0 (Rb in place over ob) ----
    {
        const int o2 = tid & 63, g = tid >> 6;
        float wA[8], wB[8];
        gemm_h128(Eh, WC4, 512, S64f, wA, wB, o2, g);
        #pragma unroll
        for (int nn = 0; nn < 8; ++nn) {
            const int n = g*8 + nn;
            const float yy = y0v[n], et = etv[n];
            int a = n*CC + o2;
            Rb[a] = INV_SQ2f * wA[nn] * Rc[a] * yy + et * Rb[a];
            a += 64;
            Rb[a] = INV_SQ2f * wB[nn] * Rc[a] * yy + et * Rb[a];
        }
    }
    __syncthreads();

    // ---- P5: GEMM1: msg0 = m0@Wl0a + m1@Wl0b + out_s@Wo0 + sc ----
    {
        const int o2 = tid & 63, g = tid >> 6;
        float accA[8], accB[8];
        #pragma unroll
        for (int nn = 0; nn < 8; ++nn) { accA[nn] = 0.0f; accB[nn] = 0.0f; }
        for (int k = 0; k < CC; k += 4) {
            const float4 la = ldw4(WL0, k,      CC, o2,      INV_2Cf);
            const float4 lb = ldw4(WL0, k,      CC, o2 + 64, INV_2Cf);
            const float4 ma = ldw4(WL0, CC + k, CC, o2,      INV_2Cf);
            const float4 mb = ldw4(WL0, CC + k, CC, o2 + 64, INV_2Cf);
            const float4 qa = ldw4(WO0, k,      CC, o2,      INV_Cf);
            const float4 qb = ldw4(WO0, k,      CC, o2 + 64, INV_Cf);
            #pragma unroll
            for (int nn = 0; nn < 8; ++nn) {
                const int base = (g*8 + nn)*CC + k;
                const float4 m0v = *(const float4*)&Rb[base];
                const float4 m1v = *(const float4*)&Ra[base];
                const float4 osv = *(const float4*)&Rc[base];
                accA[nn] += dot4(m0v, la) + dot4(m1v, ma) + dot4(osv, qa);
                accB[nn] += dot4(m0v, lb) + dot4(m1v, mb) + dot4(osv, qb);
            }
        }
        #pragma unroll
        for (int nn = 0; nn < 8; ++nn) {
            const size_t gn = (size_t)(n0 + g*8 + nn);
            OUT[gn*512 + o2]      = accA[nn] + SCp[gn*512 + o2];
            OUT[gn*512 + o2 + 64] = accB[nn] + SCp[gn*512 + o2 + 64];
        }
    }
    __syncthreads();

    // ---- P6: w2 chunk -> a2 (Rc in place): a2 = INV_SQ2*w2*out_s ----
    {
        const int o2 = tid & 63, g = tid >> 6;
        float wA[8], wB[8];
        gemm_h128(Eh, WC4 + 2*CC, 512, S64f, wA, wB, o2, g);
        #pragma unroll
        for (int nn = 0; nn < 8; ++nn) {
            const int n = g*8 + nn;
            Rc[n*CC + o2]      *= INV_SQ2f * wA[nn];
            Rc[n*CC + o2 + 64] *= INV_SQ2f * wB[nn];
        }
    }
    __syncthreads();

    // ---- P7: GEMM2: t = a2 @ Wl1[:128] * inv2c -> Rb ----
    {
        const int o2 = tid & 63, g = tid >> 6;
        float accA[8], accB[8];
        #pragma unroll
        for (int nn = 0; nn < 8; ++nn) { accA[nn] = 0.0f; accB[nn] = 0.0f; }
        for (int k = 0; k < CC; k += 4) {
            const float4 wa = ldw4(WL1, k, CC, o2,      INV_2Cf);
            const float4 wb = ldw4(WL1, k, CC, o2 + 64, INV_2Cf);
            #pragma unroll
            for (int nn = 0; nn < 8; ++nn) {
                const float4 a2v = *(const float4*)&Rc[(g*8 + nn)*CC + k];
                accA[nn] += dot4(a2v, wa);
                accB[nn] += dot4(a2v, wb);
            }
        }
        #pragma unroll
        for (int nn = 0; nn < 8; ++nn) {
            const int n = g*8 + nn;
            Rb[n*CC + o2]      = accA[nn];
            Rb[n*CC + o2 + 64] = accB[nn];
        }
    }
    __syncthreads();

    // ---- P8: w3 chunk -> b (Ra): b = INV_SQ2*w3*gate*y0 ----
    {
        const int o2 = tid & 63, g = tid >> 6;
        float wA[8], wB[8];
        gemm_h128(Eh, WC4 + 3*CC, 512, S64f, wA, wB, o2, g);
        #pragma unroll
        for (int nn = 0; nn < 8; ++nn) {
            const int n = g*8 + nn;
            const float yy = y0v[n] * INV_SQ2f;
            Ra[n*CC + o2]      = wA[nn] * Rd[n*CC + o2] * yy;
            Ra[n*CC + o2 + 64] = wB[nn] * Rd[n*CC + o2 + 64] * yy;
        }
    }
    __syncthreads();

    // ---- P9: per-i GEMMs: msg1[:,o*3+i] = (b*v_i)@Wl1b + (gate*v_i)@Wo1 + t*y1_i + sc ----
    for (int i = 0; i < 3; ++i) {
        for (int idx = tid; idx < BN*CC; idx += NT)
            Rc[idx] = Vin[(size_t)((n0 + (idx >> 7))*CC + (idx & (CC-1)))*3 + i];
        __syncthreads();
        const int o2 = tid & 63, g = tid >> 6;
        float accA[8], accB[8];
        #pragma unroll
        for (int nn = 0; nn < 8; ++nn) { accA[nn] = 0.0f; accB[nn] = 0.0f; }
        for (int k = 0; k < CC; k += 4) {
            const float4 la = ldw4(WL1, CC + k, CC, o2,      INV_2Cf);
            const float4 lb = ldw4(WL1, CC + k, CC, o2 + 64, INV_2Cf);
            const float4 qa = ldw4(WO1, k,      CC, o2,      INV_Cf);
            const float4 qb = ldw4(WO1, k,      CC, o2 + 64, INV_Cf);
            #pragma unroll
            for (int nn = 0; nn < 8; ++nn) {
                const int base = (g*8 + nn)*CC + k;
                const float4 bv = *(const float4*)&Ra[base];
                const float4 gv = *(const float4*)&Rd[base];
                const float4 ev = *(const float4*)&Rc[base];
                accA[nn] += ev.x*(bv.x*la.x + gv.x*qa.x) + ev.y*(bv.y*la.y + gv.y*qa.y)
                          + ev.z*(bv.z*la.z + gv.z*qa.z) + ev.w*(bv.w*la.w + gv.w*qa.w);
                accB[nn] += ev.x*(bv.x*lb.x + gv.x*qb.x) + ev.y*(bv.y*lb.y + gv.y*qb.y)
                          + ev.z*(bv.z*lb.z + gv.z*qb.z) + ev.w*(bv.w*lb.w + gv.w*qb.w);
            }
        }
        #pragma unroll
        for (int nn = 0; nn < 8; ++nn) {
            const int n = g*8 + nn;
            const size_t gn = (size_t)(n0 + n);
            const float yv = y1v[n*3 + i];
            {
                const size_t oi = gn*512 + CC + (size_t)o2*3 + i;
                OUT[oi] = accA[nn] + Rb[n*CC + o2]*yv + SCp[oi];
            }
            {
                const size_t oi = gn*512 + CC + (size_t)(o2 + 64)*3 + i;
                OUT[oi] = accB[nn] + Rb[n*CC + o2 + 64]*yv + SCp[oi];
            }
        }
        __syncthreads();
    }
}

extern "C" void kernel_launch(void* const* d_in, const int* in_sizes, int n_in,
                              void* d_out, int out_size, void* d_ws, size_t ws_size,
                              hipStream_t stream)
{
    (void)in_sizes; (void)n_in; (void)d_ws; (void)ws_size; (void)out_size;
    const float* Sin  = (const float*)d_in[0];
    const float* Vin  = (const float*)d_in[1];
    const float* SCp  = (const float*)d_in[2];
    const float* ATT  = (const float*)d_in[3];
    const float* INVF = (const float*)d_in[4];
    const float* MNA  = (const float*)d_in[5];
    const float* MLEN = (const float*)d_in[6];
    const float* WSp  = (const float*)d_in[7];
    const float* WVp  = (const float*)d_in[8];
    const float* WC1  = (const float*)d_in[9];
    const float* WC2  = (const float*)d_in[10];
    const float* WC3  = (const float*)d_in[11];
    const float* WC4  = (const float*)d_in[12];
    const float* WB1  = (const float*)d_in[13];
    const float* WB2  = (const float*)d_in[14];
    const float* WB3  = (const float*)d_in[15];
    const float* WB4  = (const float*)d_in[16];
    const float* ESC  = (const float*)d_in[17];
    const float* WL0  = (const float*)d_in[18];
    const float* WL1  = (const float*)d_in[19];
    const float* WO0  = (const float*)d_in[20];
    const float* WO1  = (const float*)d_in[21];
    float* OUT = (float*)d_out;

    // dynamic LDS: 4*[64][128] + [64][64] + [64][16] + 64 + 192 + 64 floats
    const size_t shbytes = (size_t)(4*BN*CC + BN*64 + BN*16 + BN + BN*3 + BN) * sizeof(float);
    (void)hipFuncSetAttribute((const void*)epb_fused,
                              hipFuncAttributeMaxDynamicSharedMemorySize, (int)shbytes);
    hipLaunchKernelGGL(epb_fused, dim3(NNODES/BN), dim3(NT), shbytes, stream,
                       Sin, Vin, SCp, ATT, INVF, MNA, MLEN, WSp, WVp,
                       WC1, WC2, WC3, WC4, WB1, WB2, WB3, WB4, ESC,
                       WL0, WL1, WO0, WO1, OUT);
}

// Round 2
// 293.874 us; speedup vs baseline: 2.9344x; 2.9344x over previous
//
#include <hip/hip_runtime.h>

#define NNODES 65536
#define CC 128
#define NEL 10
#define BN 64
#define NT 512

#define INV_SQ2f 0.70710678118654752440f
#define INV_SQ6f 0.40824829046386301637f
#define INV_2Cf  0.0625f               /* 1/sqrt(256) */
#define INV_Cf   0.08838834764831845f  /* 1/sqrt(128) */
#define S16f 0.25f
#define S64f 0.125f

#define WS_FRAGS 312
#define WS_BYTES (WS_FRAGS * 1024)

typedef __attribute__((ext_vector_type(8))) short s16x8;
typedef __attribute__((ext_vector_type(4))) float f32x4;
#define MFMA16(a, b, c) __builtin_amdgcn_mfma_f32_16x16x32_bf16((a), (b), (c), 0, 0, 0)

union U8 { unsigned short u[8]; s16x8 s; };

__device__ __forceinline__ unsigned short bf16rne(float x) {
    unsigned int u = __float_as_uint(x);
    return (unsigned short)((u + 0x7FFFu + ((u >> 16) & 1u)) >> 16);
}
__device__ __forceinline__ float bf2f(unsigned short h) {
    return __uint_as_float(((unsigned int)h) << 16);
}
__device__ __forceinline__ unsigned int packbf(float a, float b) {
    return (unsigned int)bf16rne(a) | (((unsigned int)bf16rne(b)) << 16);
}
__device__ __forceinline__ float siluf(float x) {
    return x * (1.0f / (1.0f + __expf(-x)));
}

// ---------------- weight fragment prep (one-shot, 312 frags) ----------------
// frag f of matrix (K x N): lane l holds 8 bf16 along K:
//   col n = nt*16 + (l&15), k = ks*32 + (l>>4)*8 + j  (zero if k>=K)
extern "C" __global__ void prep_frags(
    const float* __restrict__ WC1, const float* __restrict__ WC2,
    const float* __restrict__ WC3, const float* __restrict__ WB1,
    const float* __restrict__ WB2, const float* __restrict__ WB3,
    const float* __restrict__ WC4, const float* __restrict__ WB4,
    const float* __restrict__ WL0, const float* __restrict__ WO0,
    const float* __restrict__ WL1, const float* __restrict__ WO1,
    unsigned short* __restrict__ wsb)
{
    const int b = blockIdx.x;
    const int l = threadIdx.x;
    const float* W; int K, N, nKS, base; float sc;
    if      (b <  4) { W = WC1; K = 16;  N = 64;  nKS = 1; base = 0;   sc = S16f; }
    else if (b < 12) { W = WC2; K = 64;  N = 64;  nKS = 2; base = 4;   sc = S64f; }
    else if (b < 20) { W = WC3; K = 64;  N = 64;  nKS = 2; base = 12;  sc = S64f; }
    else if (b < 24) { W = WB1; K = 16;  N = 64;  nKS = 1; base = 20;  sc = S16f; }
    else if (b < 32) { W = WB2; K = 64;  N = 64;  nKS = 2; base = 24;  sc = S64f; }
    else if (b < 40) { W = WB3; K = 64;  N = 64;  nKS = 2; base = 32;  sc = S64f; }
    else if (b < 104){ W = WC4; K = 64;  N = 512; nKS = 2; base = 40;  sc = S64f; }
    else if (b < 120){ W = WB4; K = 64;  N = 128; nKS = 2; base = 104; sc = S64f; }
    else if (b < 184){ W = WL0; K = 256; N = 128; nKS = 8; base = 120; sc = INV_2Cf; }
    else if (b < 216){ W = WO0; K = 128; N = 128; nKS = 4; base = 184; sc = INV_Cf; }
    else if (b < 280){ W = WL1; K = 256; N = 128; nKS = 8; base = 216; sc = INV_2Cf; }
    else             { W = WO1; K = 128; N = 128; nKS = 4; base = 280; sc = INV_Cf; }
    const int f  = b - base;
    const int nt = f / nKS, ks = f % nKS;
    const int n  = nt * 16 + (l & 15);
    const int k0 = ks * 32 + (l >> 4) * 8;
    U8 v;
    #pragma unroll
    for (int j = 0; j < 8; ++j) {
        const int k = k0 + j;
        const float x = (k < K) ? W[(size_t)k * N + n] * sc : 0.0f;
        v.u[j] = bf16rne(x);
    }
    *(s16x8*)(wsb + (size_t)b * 512 + l * 8) = v.s;
}

// ---------------- helpers ----------------
__device__ __forceinline__ s16x8 ldB(const unsigned short* __restrict__ wsb, int fragidx, int lane) {
    return *(const s16x8*)(wsb + ((size_t)fragidx << 9) + lane * 8);
}
__device__ __forceinline__ s16x8 ldA136(const unsigned short* X, int row, int ks, int gq) {
    return *(const s16x8*)(X + row * 136 + ks * 32 + gq * 8);
}

// w-chunk GEMM: out[tc] = h3c-rows x WC4-chunk-q columns (K=64)
__device__ __forceinline__ void wchunk4(const unsigned short* __restrict__ wsb, int lane,
                                        int wbase, int ch, s16x8 h0, s16x8 h1, f32x4 wc[4]) {
    const f32x4 Z4 = {0.f, 0.f, 0.f, 0.f};
    #pragma unroll
    for (int tc = 0; tc < 4; ++tc) {
        const int nb = wbase + (ch * 4 + tc) * 2;
        f32x4 c = MFMA16(h0, ldB(wsb, nb, lane), Z4);
        wc[tc]  = MFMA16(h1, ldB(wsb, nb + 1, lane), c);
    }
}

// MLP hidden layer (64x64, K=64) with silu, H stride = 72 ushorts
__device__ __forceinline__ void mlp_layer(const unsigned short* __restrict__ wsb, int lane,
                                          int ng, int chm, int cl, int gq,
                                          const unsigned short* srcH, int bbase,
                                          unsigned short* dstH) {
    const f32x4 Z4 = {0.f, 0.f, 0.f, 0.f};
    const int rowA = ng * 16 + cl;
    f32x4 c0 = Z4, c1 = Z4;
    #pragma unroll
    for (int ks = 0; ks < 2; ++ks) {
        s16x8 a = *(const s16x8*)(srcH + rowA * 72 + ks * 32 + gq * 8);
        c0 = MFMA16(a, ldB(wsb, bbase + (chm * 2 + 0) * 2 + ks, lane), c0);
        c1 = MFMA16(a, ldB(wsb, bbase + (chm * 2 + 1) * 2 + ks, lane), c1);
    }
    #pragma unroll
    for (int r = 0; r < 4; ++r) {
        const int rw = ng * 16 + gq * 4 + r;
        dstH[rw * 72 + (chm * 2 + 0) * 16 + cl] = bf16rne(siluf(c0[r]));
        dstH[rw * 72 + (chm * 2 + 1) * 16 + cl] = bf16rne(siluf(c1[r]));
    }
}

// ---------------- main fused MFMA kernel ----------------
extern "C" __global__ void __launch_bounds__(NT)
epb_mfma(const float* __restrict__ Sin, const float* __restrict__ Vin,
         const float* __restrict__ SCp, const float* __restrict__ ATT,
         const float* __restrict__ INVF, const float* __restrict__ MNA,
         const float* __restrict__ MLEN, const float* __restrict__ WSp,
         const float* __restrict__ WVp, const float* __restrict__ ESC,
         const unsigned short* __restrict__ wsb, float* __restrict__ OUT)
{
    extern __shared__ char smem[];
    unsigned short* X1 = (unsigned short*)smem;            // m0 / H-ping / a2 / bv
    unsigned short* X2 = X1 + 8704;                        // m1 / H-pong / b
    unsigned short* X3 = X2 + 8704;                        // out_s / gv
    unsigned short* Xg = X3 + 8704;                        // gate
    float* y0f  = (float*)(smem + 69632);                  // [64]
    float* y1f  = y0f + 64;                                // [64][3]
    float* etf  = y1f + 192;                               // [64]
    int*   eidx = (int*)(smem + 70912);                    // [64]

    const int tid  = threadIdx.x;
    const int n0   = blockIdx.x * BN;
    const int wid  = tid >> 6;
    const int lane = tid & 63;
    const int ng   = wid >> 1;       // node group (16 rows)
    const int ch   = wid & 1;        // col half (64 cols) for 128-wide GEMMs
    const int chm  = wid & 1;        // col half (32 cols) for 64-wide MLP
    const int cl   = lane & 15;
    const int gq   = lane >> 4;
    const int rowA = ng * 16 + cl;
    const f32x4 Z4 = {0.f, 0.f, 0.f, 0.f};

    // ---- invl A-fragment (K=16 padded to 32) straight from global ----
    U8 invu;
    if (gq < 2) {
        const float* ip = INVF + (size_t)(n0 + rowA) * 16 + gq * 8;
        #pragma unroll
        for (int j = 0; j < 8; ++j) invu.u[j] = bf16rne(ip[j]);
    } else {
        #pragma unroll
        for (int j = 0; j < 8; ++j) invu.u[j] = 0;
    }
    const s16x8 invf = invu.s;

    // ---- P0: per-node smalls ----
    if (tid < BN) {
        const int gn = n0 + tid;
        y0f[tid] = MNA[gn * 4 + 0];
        y1f[tid * 3 + 0] = MNA[gn * 4 + 1];
        y1f[tid * 3 + 1] = MNA[gn * 4 + 2];
        y1f[tid * 3 + 2] = MNA[gn * 4 + 3];
        etf[tid] = 1.0f - __expf(-ESC[0] * MLEN[gn]);
        int e = 0;
        #pragma unroll
        for (int k = 0; k < NEL; ++k)
            if (ATT[(size_t)gn * NEL + k] > 0.5f) e = k;
        eidx[tid] = e;
    }

    // ---- MLP chain c: WC1 -> WC2 -> WC3 (H ping-pong in X1/X2, stride 72) ----
    {   // L1c: invf @ WC1 -> X1
        f32x4 c0 = MFMA16(invf, ldB(wsb, 0 + chm * 2 + 0, lane), Z4);
        f32x4 c1 = MFMA16(invf, ldB(wsb, 0 + chm * 2 + 1, lane), Z4);
        #pragma unroll
        for (int r = 0; r < 4; ++r) {
            const int rw = ng * 16 + gq * 4 + r;
            X1[rw * 72 + (chm * 2 + 0) * 16 + cl] = bf16rne(siluf(c0[r]));
            X1[rw * 72 + (chm * 2 + 1) * 16 + cl] = bf16rne(siluf(c1[r]));
        }
    }
    __syncthreads();
    mlp_layer(wsb, lane, ng, chm, cl, gq, X1, 4, X2);   __syncthreads();
    mlp_layer(wsb, lane, ng, chm, cl, gq, X2, 12, X1);  __syncthreads();
    // h3c fragments -> regs
    s16x8 h3c0 = *(const s16x8*)(X1 + rowA * 72 + 0 * 32 + gq * 8);
    s16x8 h3c1 = *(const s16x8*)(X1 + rowA * 72 + 1 * 32 + gq * 8);

    // ---- MLP chain b: WB1 -> WB2 -> WB3 ----
    {   // L1b -> X2
        f32x4 c0 = MFMA16(invf, ldB(wsb, 20 + chm * 2 + 0, lane), Z4);
        f32x4 c1 = MFMA16(invf, ldB(wsb, 20 + chm * 2 + 1, lane), Z4);
        #pragma unroll
        for (int r = 0; r < 4; ++r) {
            const int rw = ng * 16 + gq * 4 + r;
            X2[rw * 72 + (chm * 2 + 0) * 16 + cl] = bf16rne(siluf(c0[r]));
            X2[rw * 72 + (chm * 2 + 1) * 16 + cl] = bf16rne(siluf(c1[r]));
        }
    }
    __syncthreads();
    mlp_layer(wsb, lane, ng, chm, cl, gq, X2, 24, X1);  __syncthreads();
    mlp_layer(wsb, lane, ng, chm, cl, gq, X1, 32, X2);  __syncthreads();
    s16x8 h3b0 = *(const s16x8*)(X2 + rowA * 72 + 0 * 32 + gq * 8);
    s16x8 h3b1 = *(const s16x8*)(X2 + rowA * 72 + 1 * 32 + gq * 8);

    // ---- ob = h3b @ WB4 (K=64) -> C-regs ----
    f32x4 obacc[4];
    #pragma unroll
    for (int tc = 0; tc < 4; ++tc) {
        const int nb = 104 + (ch * 4 + tc) * 2;
        f32x4 c = MFMA16(h3b0, ldB(wsb, nb, lane), Z4);
        obacc[tc] = MFMA16(h3b1, ldB(wsb, nb + 1, lane), c);
    }

    // ---- P2: out_s -> X3 (bf16), gate -> Xg (bf16), thread-linear ----
    {
        const int row = tid >> 3;
        const int c0  = (tid & 7) << 4;
        const size_t gn = (size_t)(n0 + row);
        const int e = eidx[row];
        const float* sp  = Sin + gn * CC + c0;
        const float* vp  = Vin + (gn * CC + c0) * 3;
        const float* wsp = WSp + ((size_t)e * 5) * CC + c0;
        const float* wvp = WVp + ((size_t)e * 4) * CC + c0;
        unsigned int* X3d = (unsigned int*)X3;
        unsigned int* Xgd = (unsigned int*)Xg;
        const int dbase = row * 68 + (c0 >> 1);
        #pragma unroll
        for (int jp = 0; jp < 8; ++jp) {
            const int c = 2 * jp;
            const float2 s2 = *(const float2*)(sp + c);
            const float2 va = *(const float2*)(vp + 3 * c);
            const float2 vb = *(const float2*)(vp + 3 * c + 2);
            const float2 vc = *(const float2*)(vp + 3 * c + 4);
            const float vv0 = va.x * va.x + va.y * va.y + vb.x * vb.x;
            const float vv1 = vb.y * vb.y + vc.x * vc.x + vc.y * vc.y;
            const float2 p0 = *(const float2*)(wsp + 0 * CC + c);
            const float2 p1 = *(const float2*)(wsp + 1 * CC + c);
            const float2 p2 = *(const float2*)(wsp + 2 * CC + c);
            const float2 p3 = *(const float2*)(wsp + 3 * CC + c);
            const float2 p4 = *(const float2*)(wsp + 4 * CC + c);
            const float2 q0 = *(const float2*)(wvp + 0 * CC + c);
            const float2 q1 = *(const float2*)(wvp + 1 * CC + c);
            const float2 q2 = *(const float2*)(wvp + 2 * CC + c);
            const float2 q3 = *(const float2*)(wvp + 3 * CC + c);
            const float s0 = s2.x, s1 = s2.y;
            const float ss0 = s0 * s0, ss1 = s1 * s1;
            const float os0 = p0.x * s0 + p1.x * ss0 + p2.x * vv0 + p3.x * (ss0 * s0) + p4.x * (s0 * vv0);
            const float os1 = p0.y * s1 + p1.y * ss1 + p2.y * vv1 + p3.y * (ss1 * s1) + p4.y * (s1 * vv1);
            const float gt0 = q0.x + q1.x * s0 + q2.x * ss0 + q3.x * vv0;
            const float gt1 = q0.y + q1.y * s1 + q2.y * ss1 + q3.y * vv1;
            X3d[dbase + jp] = packbf(os0, os1);
            Xgd[dbase + jp] = packbf(gt0, gt1);
        }
    }
    __syncthreads();

    // ---- m1 = INV_SQ6 * w1 * gate * (v . y1) -> X2 ----
    {
        f32x4 wc[4];
        wchunk4(wsb, lane, 40 + 8 * 2, ch, h3c0, h3c1, wc);   // chunk q=1
        #pragma unroll
        for (int tc = 0; tc < 4; ++tc) {
            #pragma unroll
            for (int r = 0; r < 4; ++r) {
                const int rw = ng * 16 + gq * 4 + r;
                const int col = ch * 64 + tc * 16 + cl;
                const float gt = bf2f(Xg[rw * 136 + col]);
                const float* vp = Vin + ((size_t)(n0 + rw) * CC + col) * 3;
                const float vy = vp[0] * y1f[rw * 3] + vp[1] * y1f[rw * 3 + 1] + vp[2] * y1f[rw * 3 + 2];
                X2[rw * 136 + col] = bf16rne(INV_SQ6f * wc[tc][r] * gt * vy);
            }
        }
    }
    __syncthreads();

    // ---- m0 = INV_SQ2 * w0 * out_s * y0 + et * ob -> X1 ----
    {
        f32x4 wc[4];
        wchunk4(wsb, lane, 40, ch, h3c0, h3c1, wc);           // chunk q=0
        #pragma unroll
        for (int tc = 0; tc < 4; ++tc) {
            #pragma unroll
            for (int r = 0; r < 4; ++r) {
                const int rw = ng * 16 + gq * 4 + r;
                const int col = ch * 64 + tc * 16 + cl;
                const float os = bf2f(X3[rw * 136 + col]);
                const float v = INV_SQ2f * wc[tc][r] * os * y0f[rw] + etf[rw] * obacc[tc][r];
                X1[rw * 136 + col] = bf16rne(v);
            }
        }
    }
    __syncthreads();

    // ---- G1: msg0 = [m0|m1|os] @ [Wl0a;Wl0b;Wo0] + sc ----
    {
        f32x4 acc[4] = {Z4, Z4, Z4, Z4};
        #pragma unroll
        for (int ks = 0; ks < 12; ++ks) {
            const unsigned short* Xa = (ks < 4) ? X1 : (ks < 8) ? X2 : X3;
            const s16x8 a = ldA136(Xa, rowA, ks & 3, gq);
            #pragma unroll
            for (int tc = 0; tc < 4; ++tc) {
                const int fi = (ks < 8) ? (120 + (ch * 4 + tc) * 8 + ks)
                                        : (184 + (ch * 4 + tc) * 4 + (ks - 8));
                acc[tc] = MFMA16(a, ldB(wsb, fi, lane), acc[tc]);
            }
        }
        #pragma unroll
        for (int tc = 0; tc < 4; ++tc) {
            #pragma unroll
            for (int r = 0; r < 4; ++r) {
                const int rw = ng * 16 + gq * 4 + r;
                const size_t o = (size_t)(n0 + rw) * 512 + ch * 64 + tc * 16 + cl;
                OUT[o] = acc[tc][r] + SCp[o];
            }
        }
    }
    __syncthreads();

    // ---- a2 = INV_SQ2 * w2 * out_s -> X1 ----
    {
        f32x4 wc[4];
        wchunk4(wsb, lane, 40 + 16 * 2, ch, h3c0, h3c1, wc);  // chunk q=2
        #pragma unroll
        for (int tc = 0; tc < 4; ++tc) {
            #pragma unroll
            for (int r = 0; r < 4; ++r) {
                const int rw = ng * 16 + gq * 4 + r;
                const int col = ch * 64 + tc * 16 + cl;
                X1[rw * 136 + col] = bf16rne(INV_SQ2f * wc[tc][r] * bf2f(X3[rw * 136 + col]));
            }
        }
    }
    __syncthreads();

    // ---- G2: t = a2 @ Wl1[0:128] -> regs ;  b = INV_SQ2*w3*gate*y0 -> X2 ----
    f32x4 tacc[4] = {Z4, Z4, Z4, Z4};
    {
        #pragma unroll
        for (int ks = 0; ks < 4; ++ks) {
            const s16x8 a = ldA136(X1, rowA, ks, gq);
            #pragma unroll
            for (int tc = 0; tc < 4; ++tc)
                tacc[tc] = MFMA16(a, ldB(wsb, 216 + (ch * 4 + tc) * 8 + ks, lane), tacc[tc]);
        }
        f32x4 wc[4];
        wchunk4(wsb, lane, 40 + 24 * 2, ch, h3c0, h3c1, wc);  // chunk q=3
        #pragma unroll
        for (int tc = 0; tc < 4; ++tc) {
            #pragma unroll
            for (int r = 0; r < 4; ++r) {
                const int rw = ng * 16 + gq * 4 + r;
                const int col = ch * 64 + tc * 16 + cl;
                const float gt = bf2f(Xg[rw * 136 + col]);
                X2[rw * 136 + col] = bf16rne(INV_SQ2f * wc[tc][r] * gt * y0f[rw]);
            }
        }
    }
    __syncthreads();

    // ---- G3: per component i: [b*v_i | gate*v_i] @ [Wl1b; Wo1], acc in regs ----
    f32x4 acc3[3][4];
    #pragma unroll
    for (int i = 0; i < 3; ++i) {
        #pragma unroll
        for (int tc = 0; tc < 4; ++tc) acc3[i][tc] = Z4;
        // linear pass: bv -> X1, gv -> X3
        {
            const int row = tid >> 3;
            const int c0  = (tid & 7) << 4;
            const size_t gn = (size_t)(n0 + row);
            const unsigned int* X2d = (const unsigned int*)X2;
            const unsigned int* Xgd = (const unsigned int*)Xg;
            unsigned int* X1d = (unsigned int*)X1;
            unsigned int* X3d = (unsigned int*)X3;
            const int dbase = row * 68 + (c0 >> 1);
            #pragma unroll
            for (int jp = 0; jp < 8; ++jp) {
                const int c = c0 + 2 * jp;
                const unsigned int bd = X2d[dbase + jp];
                const unsigned int gd = Xgd[dbase + jp];
                const float v0 = Vin[(gn * CC + c) * 3 + i];
                const float v1 = Vin[(gn * CC + c + 1) * 3 + i];
                X1d[dbase + jp] = packbf(bf2f((unsigned short)(bd & 0xffff)) * v0,
                                         bf2f((unsigned short)(bd >> 16)) * v1);
                X3d[dbase + jp] = packbf(bf2f((unsigned short)(gd & 0xffff)) * v0,
                                         bf2f((unsigned short)(gd >> 16)) * v1);
            }
        }
        __syncthreads();
        #pragma unroll
        for (int ks = 0; ks < 8; ++ks) {
            const unsigned short* Xa = (ks < 4) ? X1 : X3;
            const s16x8 a = ldA136(Xa, rowA, ks & 3, gq);
            #pragma unroll
            for (int tc = 0; tc < 4; ++tc) {
                const int fi = (ks < 4) ? (216 + (ch * 4 + tc) * 8 + 4 + ks)
                                        : (280 + (ch * 4 + tc) * 4 + (ks - 4));
                acc3[i][tc] = MFMA16(a, ldB(wsb, fi, lane), acc3[i][tc]);
            }
        }
        __syncthreads();
    }

    // ---- epilogue: msg1 = G3 + t*y1_i + sc, contiguous stores ----
    #pragma unroll
    for (int tc = 0; tc < 4; ++tc) {
        #pragma unroll
        for (int r = 0; r < 4; ++r) {
            const int rw = ng * 16 + gq * 4 + r;
            const int col = ch * 64 + tc * 16 + cl;
            const size_t base = (size_t)(n0 + rw) * 512 + 128 + (size_t)col * 3;
            const float tv = tacc[tc][r];
            #pragma unroll
            for (int i = 0; i < 3; ++i) {
                const size_t o = base + i;
                OUT[o] = acc3[i][tc][r] + tv * y1f[rw * 3 + i] + SCp[o];
            }
        }
    }
}

// =====================================================================
// Fallback (round-1 f32 kernel) — used only if ws_size < WS_BYTES
// =====================================================================
__device__ __forceinline__ float dot4(float4 a, float4 b) {
    return a.x*b.x + a.y*b.y + a.z*b.z + a.w*b.w;
}
__device__ __forceinline__ float4 ldw4(const float* __restrict__ W, int k, int stride, int o, float sc) {
    return make_float4(W[(k+0)*stride + o]*sc, W[(k+1)*stride + o]*sc,
                       W[(k+2)*stride + o]*sc, W[(k+3)*stride + o]*sc);
}
template<int KIN, bool ACT>
__device__ __forceinline__ void layer64(const float* __restrict__ inL,
                                        const float* __restrict__ W,
                                        float* __restrict__ outL,
                                        float scale, int tid)
{
    const int j = tid & 63;
    const int g = tid >> 6;
    float acc[8];
    #pragma unroll
    for (int nn = 0; nn < 8; ++nn) acc[nn] = 0.0f;
    #pragma unroll 4
    for (int k = 0; k < KIN; ++k) {
        const float w = W[k*64 + j];
        #pragma unroll
        for (int nn = 0; nn < 8; ++nn)
            acc[nn] += inL[(g*8 + nn)*KIN + k] * w;
    }
    #pragma unroll
    for (int nn = 0; nn < 8; ++nn) {
        const float x = acc[nn] * scale;
        outL[(g*8 + nn)*64 + j] = ACT ? siluf(x) : x;
    }
}
__device__ __forceinline__ void gemm_h128(const float* __restrict__ hL,
                                          const float* __restrict__ W, int wrow,
                                          float scale, float* accA, float* accB,
                                          int o2, int g)
{
    #pragma unroll
    for (int nn = 0; nn < 8; ++nn) { accA[nn] = 0.0f; accB[nn] = 0.0f; }
    for (int k = 0; k < 64; k += 4) {
        const float4 wa = ldw4(W, k, wrow, o2, 1.0f);
        const float4 wb = ldw4(W, k, wrow, o2 + 64, 1.0f);
        #pragma unroll
        for (int nn = 0; nn < 8; ++nn) {
            const float4 h = *(const float4*)&hL[(g*8 + nn)*64 + k];
            accA[nn] += dot4(h, wa);
            accB[nn] += dot4(h, wb);
        }
    }
    #pragma unroll
    for (int nn = 0; nn < 8; ++nn) { accA[nn] *= scale; accB[nn] *= scale; }
}

extern "C" __global__ void __launch_bounds__(NT, 1)
epb_fused(const float* __restrict__ Sin, const float* __restrict__ Vin,
          const float* __restrict__ SCp, const float* __restrict__ ATT,
          const float* __restrict__ INVF, const float* __restrict__ MNA,
          const float* __restrict__ MLEN, const float* __restrict__ WSp,
          const float* __restrict__ WVp, const float* __restrict__ WC1,
          const float* __restrict__ WC2, const float* __restrict__ WC3,
          const float* __restrict__ WC4, const float* __restrict__ WB1,
          const float* __restrict__ WB2, const float* __restrict__ WB3,
          const float* __restrict__ WB4, const float* __restrict__ ESC,
          const float* __restrict__ WL0, const float* __restrict__ WL1,
          const float* __restrict__ WO0, const float* __restrict__ WO1,
          float* __restrict__ OUT)
{
    extern __shared__ float lds[];
    float* Ra   = lds;
    float* Rb   = Ra + BN*CC;
    float* Rc   = Rb + BN*CC;
    float* Rd   = Rc + BN*CC;
    float* Eh   = Rd + BN*CC;
    float* invl = Eh + BN*64;
    float* y0v  = invl + BN*16;
    float* y1v  = y0v + BN;
    float* etv  = y1v + BN*3;
    float* hping = Ra;
    float* hpong = Ra + BN*64;
    __shared__ int eidxs[BN];

    const int tid = threadIdx.x;
    const int n0  = blockIdx.x * BN;

    for (int idx = tid; idx < BN*16; idx += NT)
        invl[idx] = INVF[n0*16 + idx];
    if (tid < BN) {
        const int gn = n0 + tid;
        y0v[tid] = MNA[gn*4 + 0];
        y1v[tid*3 + 0] = MNA[gn*4 + 1];
        y1v[tid*3 + 1] = MNA[gn*4 + 2];
        y1v[tid*3 + 2] = MNA[gn*4 + 3];
        etv[tid] = 1.0f - __expf(-ESC[0] * MLEN[gn]);
        int e = 0;
        #pragma unroll
        for (int k = 0; k < NEL; ++k)
            if (ATT[gn*NEL + k] > 0.5f) e = k;
        eidxs[tid] = e;
    }
    __syncthreads();

    layer64<16, true>(invl,  WC1, hping, S16f, tid); __syncthreads();
    layer64<64, true>(hping, WC2, hpong, S64f, tid); __syncthreads();
    layer64<64, true>(hpong, WC3, Eh,    S64f, tid); __syncthreads();
    layer64<16, true>(invl,  WB1, hping, S16f, tid); __syncthreads();
    layer64<64, true>(hping, WB2, hpong, S64f, tid); __syncthreads();
    layer64<64, true>(hpong, WB3, hping, S64f, tid); __syncthreads();
    {
        const int o2 = tid & 63, g = tid >> 6;
        float oa[8], ob[8];
        gemm_h128(hping, WB4, CC, S64f, oa, ob, o2, g);
        #pragma unroll
        for (int nn = 0; nn < 8; ++nn) {
            const int n = g*8 + nn;
            Rb[n*CC + o2]      = oa[nn];
            Rb[n*CC + o2 + 64] = ob[nn];
        }
    }
    __syncthreads();

    for (int idx = tid; idx < BN*CC; idx += NT) {
        const int n = idx >> 7, c = idx & (CC-1);
        const int gn = n0 + n;
        const float s = Sin[(size_t)gn*CC + c];
        const float* vp = Vin + (size_t)(gn*CC + c)*3;
        const float v0 = vp[0], v1 = vp[1], v2 = vp[2];
        const float vv = v0*v0 + v1*v1 + v2*v2;
        const int e = eidxs[n];
        const float* wsp = WSp + (e*5)*CC + c;
        const float* wvp = WVp + (e*4)*CC + c;
        const float s2 = s*s;
        Rc[idx] = wsp[0]*s + wsp[CC]*s2 + wsp[2*CC]*vv + wsp[3*CC]*(s2*s) + wsp[4*CC]*(s*vv);
        Rd[idx] = wvp[0] + wvp[CC]*s + wvp[2*CC]*s2 + wvp[3*CC]*vv;
    }
    __syncthreads();

    {
        const int o2 = tid & 63, g = tid >> 6;
        float wA[8], wB[8];
        gemm_h128(Eh, WC4 + CC, 512, S64f, wA, wB, o2, g);
        #pragma unroll
        for (int nn = 0; nn < 8; ++nn) {
            const int n = g*8 + nn, gn = n0 + n;
            const float yy0 = y1v[n*3], yy1 = y1v[n*3+1], yy2 = y1v[n*3+2];
            {
                const float* vp = Vin + (size_t)(gn*CC + o2)*3;
                const float vy = vp[0]*yy0 + vp[1]*yy1 + vp[2]*yy2;
                Ra[n*CC + o2] = INV_SQ6f * wA[nn] * Rd[n*CC + o2] * vy;
            }
            {
                const float* vp = Vin + (size_t)(gn*CC + o2 + 64)*3;
                const float vy = vp[0]*yy0 + vp[1]*yy1 + vp[2]*yy2;
                Ra[n*CC + o2 + 64] = INV_SQ6f * wB[nn] * Rd[n*CC + o2 + 64] * vy;
            }
        }
    }
    __syncthreads();

    {
        const int o2 = tid & 63, g = tid >> 6;
        float wA[8], wB[8];
        gemm_h128(Eh, WC4, 512, S64f, wA, wB, o2, g);
        #pragma unroll
        for (int nn = 0; nn < 8; ++nn) {
            const int n = g*8 + nn;
            const float yy = y0v[n], et = etv[n];
            int a = n*CC + o2;
            Rb[a] = INV_SQ2f * wA[nn] * Rc[a] * yy + et * Rb[a];
            a += 64;
            Rb[a] = INV_SQ2f * wB[nn] * Rc[a] * yy + et * Rb[a];
        }
    }
    __syncthreads();

    {
        const int o2 = tid & 63, g = tid >> 6;
        float accA[8], accB[8];
        #pragma unroll
        for (int nn = 0; nn < 8; ++nn) { accA[nn] = 0.0f; accB[nn] = 0.0f; }
        for (int k = 0; k < CC; k += 4) {
            const float4 la = ldw4(WL0, k,      CC, o2,      INV_2Cf);
            const float4 lb = ldw4(WL0, k,      CC, o2 + 64, INV_2Cf);
            const float4 ma = ldw4(WL0, CC + k, CC, o2,      INV_2Cf);
            const float4 mb = ldw4(WL0, CC + k, CC, o2 + 64, INV_2Cf);
            const float4 qa = ldw4(WO0, k,      CC, o2,      INV_Cf);
            const float4 qb = ldw4(WO0, k,      CC, o2 + 64, INV_Cf);
            #pragma unroll
            for (int nn = 0; nn < 8; ++nn) {
                const int base = (g*8 + nn)*CC + k;
                const float4 m0v = *(const float4*)&Rb[base];
                const float4 m1v = *(const float4*)&Ra[base];
                const float4 osv = *(const float4*)&Rc[base];
                accA[nn] += dot4(m0v, la) + dot4(m1v, ma) + dot4(osv, qa);
                accB[nn] += dot4(m0v, lb) + dot4(m1v, mb) + dot4(osv, qb);
            }
        }
        #pragma unroll
        for (int nn = 0; nn < 8; ++nn) {
            const size_t gn = (size_t)(n0 + g*8 + nn);
            OUT[gn*512 + o2]      = accA[nn] + SCp[gn*512 + o2];
            OUT[gn*512 + o2 + 64] = accB[nn] + SCp[gn*512 + o2 + 64];
        }
    }
    __syncthreads();

    {
        const int o2 = tid & 63, g = tid >> 6;
        float wA[8], wB[8];
        gemm_h128(Eh, WC4 + 2*CC, 512, S64f, wA, wB, o2, g);
        #pragma unroll
        for (int nn = 0; nn < 8; ++nn) {
            const int n = g*8 + nn;
            Rc[n*CC + o2]      *= INV_SQ2f * wA[nn];
            Rc[n*CC + o2 + 64] *= INV_SQ2f * wB[nn];
        }
    }
    __syncthreads();

    {
        const int o2 = tid & 63, g = tid >> 6;
        float accA[8], accB[8];
        #pragma unroll
        for (int nn = 0; nn < 8; ++nn) { accA[nn] = 0.0f; accB[nn] = 0.0f; }
        for (int k = 0; k < CC; k += 4) {
            const float4 wa = ldw4(WL1, k, CC, o2,      INV_2Cf);
            const float4 wb = ldw4(WL1, k, CC, o2 + 64, INV_2Cf);
            #pragma unroll
            for (int nn = 0; nn < 8; ++nn) {
                const float4 a2v = *(const float4*)&Rc[(g*8 + nn)*CC + k];
                accA[nn] += dot4(a2v, wa);
                accB[nn] += dot4(a2v, wb);
            }
        }
        #pragma unroll
        for (int nn = 0; nn < 8; ++nn) {
            const int n = g*8 + nn;
            Rb[n*CC + o2]      = accA[nn];
            Rb[n*CC + o2 + 64] = accB[nn];
        }
    }
    __syncthreads();

    {
        const int o2 = tid & 63, g = tid >> 6;
        float wA[8], wB[8];
        gemm_h128(Eh, WC4 + 3*CC, 512, S64f, wA, wB, o2, g);
        #pragma unroll
        for (int nn = 0; nn < 8; ++nn) {
            const int n = g*8 + nn;
            const float yy = y0v[n] * INV_SQ2f;
            Ra[n*CC + o2]      = wA[nn] * Rd[n*CC + o2] * yy;
            Ra[n*CC + o2 + 64] = wB[nn] * Rd[n*CC + o2 + 64] * yy;
        }
    }
    __syncthreads();

    for (int i = 0; i < 3; ++i) {
        for (int idx = tid; idx < BN*CC; idx += NT)
            Rc[idx] = Vin[(size_t)((n0 + (idx >> 7))*CC + (idx & (CC-1)))*3 + i];
        __syncthreads();
        const int o2 = tid & 63, g = tid >> 6;
        float accA[8], accB[8];
        #pragma unroll
        for (int nn = 0; nn < 8; ++nn) { accA[nn] = 0.0f; accB[nn] = 0.0f; }
        for (int k = 0; k < CC; k += 4) {
            const float4 la = ldw4(WL1, CC + k, CC, o2,      INV_2Cf);
            const float4 lb = ldw4(WL1, CC + k, CC, o2 + 64, INV_2Cf);
            const float4 qa = ldw4(WO1, k,      CC, o2,      INV_Cf);
            const float4 qb = ldw4(WO1, k,      CC, o2 + 64, INV_Cf);
            #pragma unroll
            for (int nn = 0; nn < 8; ++nn) {
                const int base = (g*8 + nn)*CC + k;
                const float4 bv = *(const float4*)&Ra[base];
                const float4 gv = *(const float4*)&Rd[base];
                const float4 ev = *(const float4*)&Rc[base];
                accA[nn] += ev.x*(bv.x*la.x + gv.x*qa.x) + ev.y*(bv.y*la.y + gv.y*qa.y)
                          + ev.z*(bv.z*la.z + gv.z*qa.z) + ev.w*(bv.w*la.w + gv.w*qa.w);
                accB[nn] += ev.x*(bv.x*lb.x + gv.x*qb.x) + ev.y*(bv.y*lb.y + gv.y*qb.y)
                          + ev.z*(bv.z*lb.z + gv.z*qb.z) + ev.w*(bv.w*lb.w + gv.w*qb.w);
            }
        }
        #pragma unroll
        for (int nn = 0; nn < 8; ++nn) {
            const int n = g*8 + nn;
            const size_t gn = (size_t)(n0 + n);
            const float yv = y1v[n*3 + i];
            {
                const size_t oi = gn*512 + CC + (size_t)o2*3 + i;
                OUT[oi] = accA[nn] + Rb[n*CC + o2]*yv + SCp[oi];
            }
            {
                const size_t oi = gn*512 + CC + (size_t)(o2 + 64)*3 + i;
                OUT[oi] = accB[nn] + Rb[n*CC + o2 + 64]*yv + SCp[oi];
            }
        }
        __syncthreads();
    }
}

extern "C" void kernel_launch(void* const* d_in, const int* in_sizes, int n_in,
                              void* d_out, int out_size, void* d_ws, size_t ws_size,
                              hipStream_t stream)
{
    (void)in_sizes; (void)n_in; (void)out_size;
    const float* Sin  = (const float*)d_in[0];
    const float* Vin  = (const float*)d_in[1];
    const float* SCp  = (const float*)d_in[2];
    const float* ATT  = (const float*)d_in[3];
    const float* INVF = (const float*)d_in[4];
    const float* MNA  = (const float*)d_in[5];
    const float* MLEN = (const float*)d_in[6];
    const float* WSp  = (const float*)d_in[7];
    const float* WVp  = (const float*)d_in[8];
    const float* WC1  = (const float*)d_in[9];
    const float* WC2  = (const float*)d_in[10];
    const float* WC3  = (const float*)d_in[11];
    const float* WC4  = (const float*)d_in[12];
    const float* WB1  = (const float*)d_in[13];
    const float* WB2  = (const float*)d_in[14];
    const float* WB3  = (const float*)d_in[15];
    const float* WB4  = (const float*)d_in[16];
    const float* ESC  = (const float*)d_in[17];
    const float* WL0  = (const float*)d_in[18];
    const float* WL1  = (const float*)d_in[19];
    const float* WO0  = (const float*)d_in[20];
    const float* WO1  = (const float*)d_in[21];
    float* OUT = (float*)d_out;

    if (ws_size >= (size_t)WS_BYTES) {
        unsigned short* wsb = (unsigned short*)d_ws;
        hipLaunchKernelGGL(prep_frags, dim3(WS_FRAGS), dim3(64), 0, stream,
                           WC1, WC2, WC3, WB1, WB2, WB3, WC4, WB4,
                           WL0, WO0, WL1, WO1, wsb);
        const size_t shbytes = 71168;
        (void)hipFuncSetAttribute((const void*)epb_mfma,
                                  hipFuncAttributeMaxDynamicSharedMemorySize, (int)shbytes);
        hipLaunchKernelGGL(epb_mfma, dim3(NNODES / BN), dim3(NT), shbytes, stream,
                           Sin, Vin, SCp, ATT, INVF, MNA, MLEN, WSp, WVp, ESC,
                           wsb, OUT);
    } else {
        const size_t shbytes = (size_t)(4*BN*CC + BN*64 + BN*16 + BN + BN*3 + BN) * sizeof(float);
        (void)hipFuncSetAttribute((const void*)epb_fused,
                                  hipFuncAttributeMaxDynamicSharedMemorySize, (int)shbytes);
        hipLaunchKernelGGL(epb_fused, dim3(NNODES / BN), dim3(NT), shbytes, stream,
                           Sin, Vin, SCp, ATT, INVF, MNA, MLEN, WSp, WVp,
                           WC1, WC2, WC3, WC4, WB1, WB2, WB3, WB4, ESC,
                           WL0, WL1, WO0, WO1, OUT);
    }
}